// Round 16
// baseline (25.950 us; speedup 1.0000x reference)
//
#include <hip/hip_runtime.h>
#include <hip/hip_bf16.h>

typedef __attribute__((ext_vector_type(8))) short bf16x8;
typedef __attribute__((ext_vector_type(4))) float f32x4;

__device__ __forceinline__ unsigned short f2bf(float f) {
    unsigned u = __builtin_bit_cast(unsigned, f);
    unsigned rnd = 0x7FFFu + ((u >> 16) & 1u);
    return (unsigned short)((u + rnd) >> 16);
}

// ---------------------------------------------------------------------------
// Setup: simulate the circuit on the 256 basis vectors -> U (256x256),
// packed as bf16 fragments (B-operand map, R2/R3/R5-verified):
//   element (n,k): u=n>>4, t=k>>5, lane=((k>>3)&3)*16+(n&15), j=k&7
//   Bp[((u*8+t)*64 + lane)*8 + j]
// ---------------------------------------------------------------------------
__global__ __launch_bounds__(256) void qnn_setup(const float* __restrict__ wts,
                                                 unsigned short* __restrict__ Bp) {
    __shared__ float cs[56], sn[56];
    int tid = threadIdx.x;
    if (tid < 56) {
        float th = 0.5f * wts[tid];
        cs[tid] = cosf(th);
        sn[tid] = sinf(th);
    }
    __syncthreads();

    int l = tid & 63;
    int k = blockIdx.x * 4 + (tid >> 6);   // column 0..255
    int a0 = l << 2;

    float v0 = (float)(a0 + 0 == k);
    float v1 = (float)(a0 + 1 == k);
    float v2 = (float)(a0 + 2 == k);
    float v3 = (float)(a0 + 3 == k);

#pragma unroll
    for (int L = 0; L < 7; ++L) {
#pragma unroll
        for (int q = 0; q <= 5; ++q) {     // RY wires 0..5 (lane bits)
            int m = 5 - q;
            float c = cs[L * 8 + q], s = sn[L * 8 + q];
            float ss = ((l >> m) & 1) ? s : -s;
            float p0 = __shfl_xor(v0, 1 << m);
            float p1 = __shfl_xor(v1, 1 << m);
            float p2 = __shfl_xor(v2, 1 << m);
            float p3 = __shfl_xor(v3, 1 << m);
            v0 = fmaf(ss, p0, c * v0);
            v1 = fmaf(ss, p1, c * v1);
            v2 = fmaf(ss, p2, c * v2);
            v3 = fmaf(ss, p3, c * v3);
        }
        {   // RY wire 6 (reg bit 1)
            float c = cs[L * 8 + 6], s = sn[L * 8 + 6];
            float n0 = fmaf(-s, v2, c * v0), n2 = fmaf(s, v0, c * v2);
            float n1 = fmaf(-s, v3, c * v1), n3 = fmaf(s, v1, c * v3);
            v0 = n0; v1 = n1; v2 = n2; v3 = n3;
        }
        {   // RY wire 7 (reg bit 0)
            float c = cs[L * 8 + 7], s = sn[L * 8 + 7];
            float n0 = fmaf(-s, v1, c * v0), n1 = fmaf(s, v0, c * v1);
            float n2 = fmaf(-s, v3, c * v2), n3 = fmaf(s, v2, c * v3);
            v0 = n0; v1 = n1; v2 = n2; v3 = n3;
        }
        {   // CNOTs q=0..4 (both bits in lane index): composed lane permute
            int src = l;
#pragma unroll
            for (int q = 4; q >= 0; --q)
                src = src ^ (((src >> (5 - q)) & 1) << (4 - q));
            v0 = __shfl(v0, src);
            v1 = __shfl(v1, src);
            v2 = __shfl(v2, src);
            v3 = __shfl(v3, src);
        }
        {   // CNOT q=5: ctl = lane bit0, tgt = reg bit1
            bool cc = (l & 1);
            float n0 = cc ? v2 : v0, n2 = cc ? v0 : v2;
            float n1 = cc ? v3 : v1, n3 = cc ? v1 : v3;
            v0 = n0; v1 = n1; v2 = n2; v3 = n3;
        }
        {   // CNOT q=6: swap v2,v3
            float t = v2; v2 = v3; v3 = t;
        }
    }

    int t = k >> 5, j = k & 7, lk = (k >> 3) & 3;
#pragma unroll
    for (int r = 0; r < 4; ++r) {
        int n = a0 + r;
        int u = n >> 4;
        int ls = lk * 16 + (n & 15);
        float val = (r == 0) ? v0 : (r == 1) ? v1 : (r == 2) ? v2 : v3;
        Bp[(((u * 8 + t) * 64) + ls) * 8 + j] = f2bf(val);
    }
}

// convert 8 fp32 (two float4) -> one bf16x8 A-fragment, accumulate norm
__device__ __forceinline__ bf16x8 cvt8(const float4& a, const float4& b, float& ss) {
    ss = fmaf(a.x, a.x, fmaf(a.y, a.y, fmaf(a.z, a.z, fmaf(a.w, a.w, ss))));
    ss = fmaf(b.x, b.x, fmaf(b.y, b.y, fmaf(b.z, b.z, fmaf(b.w, b.w, ss))));
    bf16x8 h;
    h[0] = (short)f2bf(a.x); h[1] = (short)f2bf(a.y);
    h[2] = (short)f2bf(a.z); h[3] = (short)f2bf(a.w);
    h[4] = (short)f2bf(b.x); h[5] = (short)f2bf(b.y);
    h[6] = (short)f2bf(b.z); h[7] = (short)f2bf(b.w);
    return h;
}

// ---------------------------------------------------------------------------
// Main (R16): involution + barrier-free. z = 1 - 2*P-/||x||^2 needs only
// u-blocks 8..15 of U (64 KB), staged ONCE into LDS (single __syncthreads).
// After that every wave is fully independent: own 16 samples in registers
// (X-as-A, R5-verified layout), 64 linear ds_read_b128 + 64 MFMA (paired
// chains), in-wave reduce, MLP, direct store. No Qpart, no cadence —
// 16 desynced waves/CU self-hide all latency. 512 blocks x 512 thr.
// ---------------------------------------------------------------------------
__global__ __launch_bounds__(512, 4) void qnn_main(
    const float* __restrict__ x, const unsigned short* __restrict__ Bp,
    const float* __restrict__ W1, const float* __restrict__ b1,
    const float* __restrict__ W2, const float* __restrict__ b2,
    float* __restrict__ out) {
    __shared__ __align__(16) unsigned short Blds[32768];   // 64 KB: u 8..15

    int tid = threadIdx.x;
    int l = tid & 63, w = tid >> 6;                        // wave 0..7
    size_t base = (size_t)blockIdx.x * 128 * 256;          // 128 samples/block

    // lane l: sample row = 16w + (l&15), k-group kg = l>>4 (k = 32t+8kg..+7)
    const float* xr = x + base + (size_t)(16 * w + (l & 15)) * 256 + (l >> 4) * 8;

    // ---- pass 1: issue 8 loads (t=0..3), then stage U, then convert ----
    float4 fa[8];
#pragma unroll
    for (int t = 0; t < 4; ++t) {
        fa[2 * t]     = *(const float4*)(xr + t * 32);
        fa[2 * t + 1] = *(const float4*)(xr + t * 32 + 4);
    }
    {   // stage minus-half of U: wave w copies 8 KB, 16B/lane, linear dst
        const unsigned short* src = Bp + 32768 + w * 4096 + l * 8;
        unsigned short* dst = Blds + w * 4096;             // wave-uniform base
#pragma unroll
        for (int i = 0; i < 8; ++i) {
            __builtin_amdgcn_global_load_lds(
                (const __attribute__((address_space(1))) void*)(src + i * 512),
                (__attribute__((address_space(3))) void*)(dst + i * 512),
                16, 0, 0);
        }
    }
    float ss = 0.f;
    bf16x8 af[8];
#pragma unroll
    for (int t = 0; t < 4; ++t)
        af[t] = cvt8(fa[2 * t], fa[2 * t + 1], ss);
    // ---- pass 2: loads t=4..7, convert ----
#pragma unroll
    for (int t = 4; t < 8; ++t) {
        fa[2 * (t - 4)]     = *(const float4*)(xr + t * 32);
        fa[2 * (t - 4) + 1] = *(const float4*)(xr + t * 32 + 4);
    }
#pragma unroll
    for (int t = 4; t < 8; ++t)
        af[t] = cvt8(fa[2 * (t - 4)], fa[2 * (t - 4) + 1], ss);
    // norm of sample (l&15): combine the 4 k-groups
    ss += __shfl_xor(ss, 16);
    ss += __shfl_xor(ss, 32);

    __syncthreads();   // the ONLY barrier: U staged (drains vmcnt incl. DMA)

    // ---- P- : 8 u-blocks in 4 pair-iterations, linear conflict-free reads ----
    float q[4] = {0.f, 0.f, 0.f, 0.f};
    const unsigned short* bl = Blds + l * 8;
#pragma unroll
    for (int up = 0; up < 8; up += 2) {
        f32x4 a0 = {0.f, 0.f, 0.f, 0.f}, a1 = {0.f, 0.f, 0.f, 0.f};
#pragma unroll
        for (int t = 0; t < 8; ++t) {
            bf16x8 b0 = *(const bf16x8*)(bl + ((up    ) * 8 + t) * 512);
            bf16x8 b1 = *(const bf16x8*)(bl + ((up + 1) * 8 + t) * 512);
            a0 = __builtin_amdgcn_mfma_f32_16x16x32_bf16(af[t], b0, a0, 0, 0, 0);
            a1 = __builtin_amdgcn_mfma_f32_16x16x32_bf16(af[t], b1, a1, 0, 0, 0);
        }
#pragma unroll
        for (int j = 0; j < 4; ++j)
            q[j] = fmaf(a0[j], a0[j], fmaf(a1[j], a1[j], q[j]));
    }
    // reduce over the 16 n-columns (lane&15), leaving rows = samples
#pragma unroll
    for (int d = 1; d < 16; d <<= 1) {
#pragma unroll
        for (int j = 0; j < 4; ++j) q[j] += __shfl_xor(q[j], d);
    }

    // norm for the rows this lane writes (C/D: row=(l>>4)*4+j, col=l&15)
    float nrm = __shfl(ss, ((l >> 4) << 2) | (l & 3));

    if ((l & 15) < 4) {
        int j = l & 3;
        int s = 16 * w + (l >> 4) * 4 + j;
        float qv = (j == 0) ? q[0] : (j == 1) ? q[1] : (j == 2) ? q[2] : q[3];
        float z = 1.f - 2.f * qv / nrm;            // involution: P+ = N - P-
        float o = b2[0];
#pragma unroll
        for (int jj = 0; jj < 16; ++jj) {
            float h = fmaf(z, W1[jj], b1[jj]);
            h = h > 0.f ? h : 0.f;
            o = fmaf(W2[jj], h, o);
        }
        out[(size_t)blockIdx.x * 128 + s] = 1.f / (1.f + expf(-o));
    }
}

extern "C" void kernel_launch(void* const* d_in, const int* in_sizes, int n_in,
                              void* d_out, int out_size, void* d_ws, size_t ws_size,
                              hipStream_t stream) {
    const float* x   = (const float*)d_in[0];
    const float* wts = (const float*)d_in[1];
    const float* W1  = (const float*)d_in[2];
    const float* b1  = (const float*)d_in[3];
    const float* W2  = (const float*)d_in[4];
    const float* b2  = (const float*)d_in[5];
    float* out = (float*)d_out;
    unsigned short* Bp = (unsigned short*)d_ws;   // 65536 bf16 = 128 KB

    int B = in_sizes[0] >> 8;        // 65536 samples
    qnn_setup<<<64, 256, 0, stream>>>(wts, Bp);
    qnn_main<<<B / 128, 512, 0, stream>>>(x, Bp, W1, b1, W2, b2, out);
}

// Round 17
// 23.882 us; speedup vs baseline: 1.0866x; 1.0866x over previous
//
#include <hip/hip_runtime.h>
#include <hip/hip_bf16.h>

typedef __attribute__((ext_vector_type(8))) short bf16x8;
typedef __attribute__((ext_vector_type(4))) float f32x4;

__device__ __forceinline__ unsigned short f2bf(float f) {
    unsigned u = __builtin_bit_cast(unsigned, f);
    unsigned rnd = 0x7FFFu + ((u >> 16) & 1u);
    return (unsigned short)((u + rnd) >> 16);
}

// raw barrier: lgkmcnt drain (LDS writes visible) WITHOUT vmcnt drain, so
// in-flight global prefetch loads survive the barrier (R9/R12/R13-verified).
__device__ __forceinline__ void wg_barrier() {
    asm volatile("s_waitcnt lgkmcnt(0)" ::: "memory");
    __builtin_amdgcn_sched_barrier(0);
    __builtin_amdgcn_s_barrier();
    __builtin_amdgcn_sched_barrier(0);
}

// ---------------------------------------------------------------------------
// Setup: simulate the circuit on the 256 basis vectors -> U (256x256),
// packed as bf16 fragments (same map for A- or B-operand; R8-verified):
//   element (n,k): u=n>>4, t=k>>5, lane=((k>>3)&3)*16+(n&15), j=k&7
//   Bp[((u*8+t)*64 + lane)*8 + j]
// ---------------------------------------------------------------------------
__global__ __launch_bounds__(256) void qnn_setup(const float* __restrict__ wts,
                                                 unsigned short* __restrict__ Bp) {
    __shared__ float cs[56], sn[56];
    int tid = threadIdx.x;
    if (tid < 56) {
        float th = 0.5f * wts[tid];
        cs[tid] = cosf(th);
        sn[tid] = sinf(th);
    }
    __syncthreads();

    int l = tid & 63;
    int k = blockIdx.x * 4 + (tid >> 6);   // column 0..255
    int a0 = l << 2;

    float v0 = (float)(a0 + 0 == k);
    float v1 = (float)(a0 + 1 == k);
    float v2 = (float)(a0 + 2 == k);
    float v3 = (float)(a0 + 3 == k);

#pragma unroll
    for (int L = 0; L < 7; ++L) {
#pragma unroll
        for (int q = 0; q <= 5; ++q) {     // RY wires 0..5 (lane bits)
            int m = 5 - q;
            float c = cs[L * 8 + q], s = sn[L * 8 + q];
            float ss = ((l >> m) & 1) ? s : -s;
            float p0 = __shfl_xor(v0, 1 << m);
            float p1 = __shfl_xor(v1, 1 << m);
            float p2 = __shfl_xor(v2, 1 << m);
            float p3 = __shfl_xor(v3, 1 << m);
            v0 = fmaf(ss, p0, c * v0);
            v1 = fmaf(ss, p1, c * v1);
            v2 = fmaf(ss, p2, c * v2);
            v3 = fmaf(ss, p3, c * v3);
        }
        {   // RY wire 6 (reg bit 1)
            float c = cs[L * 8 + 6], s = sn[L * 8 + 6];
            float n0 = fmaf(-s, v2, c * v0), n2 = fmaf(s, v0, c * v2);
            float n1 = fmaf(-s, v3, c * v1), n3 = fmaf(s, v1, c * v3);
            v0 = n0; v1 = n1; v2 = n2; v3 = n3;
        }
        {   // RY wire 7 (reg bit 0)
            float c = cs[L * 8 + 7], s = sn[L * 8 + 7];
            float n0 = fmaf(-s, v1, c * v0), n1 = fmaf(s, v0, c * v1);
            float n2 = fmaf(-s, v3, c * v2), n3 = fmaf(s, v2, c * v3);
            v0 = n0; v1 = n1; v2 = n2; v3 = n3;
        }
        {   // CNOTs q=0..4 (both bits in lane index): composed lane permute
            int src = l;
#pragma unroll
            for (int q = 4; q >= 0; --q)
                src = src ^ (((src >> (5 - q)) & 1) << (4 - q));
            v0 = __shfl(v0, src);
            v1 = __shfl(v1, src);
            v2 = __shfl(v2, src);
            v3 = __shfl(v3, src);
        }
        {   // CNOT q=5: ctl = lane bit0, tgt = reg bit1
            bool cc = (l & 1);
            float n0 = cc ? v2 : v0, n2 = cc ? v0 : v2;
            float n1 = cc ? v3 : v1, n3 = cc ? v1 : v3;
            v0 = n0; v1 = n1; v2 = n2; v3 = n3;
        }
        {   // CNOT q=6: swap v2,v3
            float t = v2; v2 = v3; v3 = t;
        }
    }

    int t = k >> 5, j = k & 7, lk = (k >> 3) & 3;
#pragma unroll
    for (int r = 0; r < 4; ++r) {
        int n = a0 + r;
        int u = n >> 4;
        int ls = lk * 16 + (n & 15);
        float val = (r == 0) ? v0 : (r == 1) ? v1 : (r == 2) ? v2 : v3;
        Bp[(((u * 8 + t) * 64) + ls) * 8 + j] = f2bf(val);
    }
}

// convert one thread's 8 floats of a 16-row tile, store swizzled.
// No norm path: U orthogonal -> denominator = P+ + P- (R13-verified).
__device__ __forceinline__ void cvt_store(const float4& a, const float4& b,
                                          unsigned short (*Xp)[256],
                                          int sr, int qt) {
    bf16x8 h;
    h[0] = (short)f2bf(a.x); h[1] = (short)f2bf(a.y);
    h[2] = (short)f2bf(a.z); h[3] = (short)f2bf(a.w);
    h[4] = (short)f2bf(b.x); h[5] = (short)f2bf(b.y);
    h[6] = (short)f2bf(b.z); h[7] = (short)f2bf(b.w);
    *(bf16x8*)&Xp[sr][(qt ^ (sr & 7)) * 8] = h;       // bijective XOR swizzle
}

// ---------------------------------------------------------------------------
// Main (R17): R13's verified skeleton, re-decomposed as 1024 blocks x 512
// thr x 64 samples (4 phases). 2 resident blocks/CU PLUS a 2-deep block
// queue: generation-2 prologues overlap generation-1 drains, prologue storm
// halved, fill/drain amortized across generations. All inner mechanics
// (16-sample tiles, depth-2 prefetch, lgkm-only barriers, z=(P+-P-)/(P++P-))
// identical to R13.
// ---------------------------------------------------------------------------
__global__ __launch_bounds__(512, 4) void qnn_main(
    const float* __restrict__ x, const unsigned short* __restrict__ Bp,
    const float* __restrict__ W1, const float* __restrict__ b1,
    const float* __restrict__ W2, const float* __restrict__ b2,
    float* __restrict__ out) {
    __shared__ __align__(16) unsigned short Xs[2][16][256];   // 16 KB
    __shared__ float Qpart[8][64];                            // 2 KB

    int tid = threadIdx.x;
    int l = tid & 63, w = tid >> 6;        // wave 0..7
    int sr = tid >> 5, qt = tid & 31;      // staging: row 0..15, 8-float chunk
    size_t base = (size_t)blockIdx.x * 64 * 256;   // 64 samples/block
    const float* xst = x + base + (size_t)sr * 256 + qt * 8;

    // ---- U fragments (u-blocks 2w, 2w+1), loaded once ----
    const unsigned short* up = Bp + (size_t)(2 * w) * 4096 + l * 8;
    bf16x8 uf0[8], uf1[8];
#pragma unroll
    for (int t = 0; t < 8; ++t) {
        uf0[t] = *(const bf16x8*)(up + t * 512);
        uf1[t] = *(const bf16x8*)(up + 4096 + t * 512);
    }

    // ---- prologue: tiles 0,1 prefetched; tile 0 converted to LDS ----
    float4 pf[2][2];
    pf[0][0] = *(const float4*)(xst);
    pf[0][1] = *(const float4*)(xst + 4);
    pf[1][0] = *(const float4*)(xst + 4096);
    pf[1][1] = *(const float4*)(xst + 4100);
    cvt_store(pf[0][0], pf[0][1], Xs[0], sr, qt);
    wg_barrier();

    int row = l & 15, kg = l >> 4;

    // ---- 4-tile pipeline: prefetch(t+2) -> compute(t) -> cvt_store(t+1) ----
#pragma unroll
    for (int t = 0; t < 4; ++t) {
        if (t + 2 < 4) {
            pf[t & 1][0] = *(const float4*)(xst + (size_t)(t + 2) * 4096);
            pf[t & 1][1] = *(const float4*)(xst + (size_t)(t + 2) * 4096 + 4);
        }
        {   // compute tile t: 8 ksteps x 2 builtin MFMAs
            const unsigned short* rp = &Xs[t & 1][row][0];
            f32x4 a0 = {0.f, 0.f, 0.f, 0.f}, a1 = {0.f, 0.f, 0.f, 0.f};
#pragma unroll
            for (int ks = 0; ks < 8; ++ks) {
                bf16x8 xf = *(const bf16x8*)(rp + (((ks << 2) | kg) ^ (row & 7)) * 8);
                a0 = __builtin_amdgcn_mfma_f32_16x16x32_bf16(uf0[ks], xf, a0, 0, 0, 0);
                a1 = __builtin_amdgcn_mfma_f32_16x16x32_bf16(uf1[ks], xf, a1, 0, 0, 0);
            }
            float q = 0.f;
#pragma unroll
            for (int j = 0; j < 4; ++j)
                q = fmaf(a0[j], a0[j], fmaf(a1[j], a1[j], q));
            q += __shfl_xor(q, 16);        // reduce the 4 n-row groups
            q += __shfl_xor(q, 32);
            if (l < 16) Qpart[w][t * 16 + l] = q;
        }
        if (t + 1 < 4)
            cvt_store(pf[(t + 1) & 1][0], pf[(t + 1) & 1][1],
                      Xs[(t + 1) & 1], sr, qt);
        wg_barrier();
    }

    // ---- epilogue: z = (P+ - P-)/(P+ + P-), MLP, sigmoid ----
    if (tid < 64) {
        float pp = Qpart[0][tid] + Qpart[1][tid] + Qpart[2][tid] + Qpart[3][tid];
        float pm = Qpart[4][tid] + Qpart[5][tid] + Qpart[6][tid] + Qpart[7][tid];
        float z = (pp - pm) / (pp + pm);
        float o = b2[0];
#pragma unroll
        for (int jj = 0; jj < 16; ++jj) {
            float h = fmaf(z, W1[jj], b1[jj]);
            h = h > 0.f ? h : 0.f;
            o = fmaf(W2[jj], h, o);
        }
        out[(size_t)blockIdx.x * 64 + tid] = 1.f / (1.f + expf(-o));
    }
}

extern "C" void kernel_launch(void* const* d_in, const int* in_sizes, int n_in,
                              void* d_out, int out_size, void* d_ws, size_t ws_size,
                              hipStream_t stream) {
    const float* x   = (const float*)d_in[0];
    const float* wts = (const float*)d_in[1];
    const float* W1  = (const float*)d_in[2];
    const float* b1  = (const float*)d_in[3];
    const float* W2  = (const float*)d_in[4];
    const float* b2  = (const float*)d_in[5];
    float* out = (float*)d_out;
    unsigned short* Bp = (unsigned short*)d_ws;   // 65536 bf16 = 128 KB

    int B = in_sizes[0] >> 8;        // 65536 samples
    qnn_setup<<<64, 256, 0, stream>>>(wts, Bp);
    qnn_main<<<B / 64, 512, 0, stream>>>(x, Bp, W1, b1, W2, b2, out);
}

// Round 18
// 22.557 us; speedup vs baseline: 1.1504x; 1.0587x over previous
//
#include <hip/hip_runtime.h>
#include <hip/hip_bf16.h>

typedef __attribute__((ext_vector_type(8))) short bf16x8;
typedef __attribute__((ext_vector_type(4))) float f32x4;

__device__ __forceinline__ unsigned short f2bf(float f) {
    unsigned u = __builtin_bit_cast(unsigned, f);
    unsigned rnd = 0x7FFFu + ((u >> 16) & 1u);
    return (unsigned short)((u + rnd) >> 16);
}

// raw barrier: lgkmcnt drain only; in-flight global prefetch survives
// (R9/R12/R13-verified).
__device__ __forceinline__ void wg_barrier() {
    asm volatile("s_waitcnt lgkmcnt(0)" ::: "memory");
    __builtin_amdgcn_sched_barrier(0);
    __builtin_amdgcn_s_barrier();
    __builtin_amdgcn_sched_barrier(0);
}

// ---------------------------------------------------------------------------
// Setup: simulate the circuit on the 256 basis vectors -> U (256x256),
// packed as bf16 fragments (same map for A- or B-operand; R8-verified):
//   element (n,k): u=n>>4, t=k>>5, lane=((k>>3)&3)*16+(n&15), j=k&7
//   Bp[((u*8+t)*64 + lane)*8 + j]
// ---------------------------------------------------------------------------
__global__ __launch_bounds__(256) void qnn_setup(const float* __restrict__ wts,
                                                 unsigned short* __restrict__ Bp) {
    __shared__ float cs[56], sn[56];
    int tid = threadIdx.x;
    if (tid < 56) {
        float th = 0.5f * wts[tid];
        cs[tid] = cosf(th);
        sn[tid] = sinf(th);
    }
    __syncthreads();

    int l = tid & 63;
    int k = blockIdx.x * 4 + (tid >> 6);   // column 0..255
    int a0 = l << 2;

    float v0 = (float)(a0 + 0 == k);
    float v1 = (float)(a0 + 1 == k);
    float v2 = (float)(a0 + 2 == k);
    float v3 = (float)(a0 + 3 == k);

#pragma unroll
    for (int L = 0; L < 7; ++L) {
#pragma unroll
        for (int q = 0; q <= 5; ++q) {     // RY wires 0..5 (lane bits)
            int m = 5 - q;
            float c = cs[L * 8 + q], s = sn[L * 8 + q];
            float ss = ((l >> m) & 1) ? s : -s;
            float p0 = __shfl_xor(v0, 1 << m);
            float p1 = __shfl_xor(v1, 1 << m);
            float p2 = __shfl_xor(v2, 1 << m);
            float p3 = __shfl_xor(v3, 1 << m);
            v0 = fmaf(ss, p0, c * v0);
            v1 = fmaf(ss, p1, c * v1);
            v2 = fmaf(ss, p2, c * v2);
            v3 = fmaf(ss, p3, c * v3);
        }
        {   // RY wire 6 (reg bit 1)
            float c = cs[L * 8 + 6], s = sn[L * 8 + 6];
            float n0 = fmaf(-s, v2, c * v0), n2 = fmaf(s, v0, c * v2);
            float n1 = fmaf(-s, v3, c * v1), n3 = fmaf(s, v1, c * v3);
            v0 = n0; v1 = n1; v2 = n2; v3 = n3;
        }
        {   // RY wire 7 (reg bit 0)
            float c = cs[L * 8 + 7], s = sn[L * 8 + 7];
            float n0 = fmaf(-s, v1, c * v0), n1 = fmaf(s, v0, c * v1);
            float n2 = fmaf(-s, v3, c * v2), n3 = fmaf(s, v2, c * v3);
            v0 = n0; v1 = n1; v2 = n2; v3 = n3;
        }
        {   // CNOTs q=0..4 (both bits in lane index): composed lane permute
            int src = l;
#pragma unroll
            for (int q = 4; q >= 0; --q)
                src = src ^ (((src >> (5 - q)) & 1) << (4 - q));
            v0 = __shfl(v0, src);
            v1 = __shfl(v1, src);
            v2 = __shfl(v2, src);
            v3 = __shfl(v3, src);
        }
        {   // CNOT q=5: ctl = lane bit0, tgt = reg bit1
            bool cc = (l & 1);
            float n0 = cc ? v2 : v0, n2 = cc ? v0 : v2;
            float n1 = cc ? v3 : v1, n3 = cc ? v1 : v3;
            v0 = n0; v1 = n1; v2 = n2; v3 = n3;
        }
        {   // CNOT q=6: swap v2,v3
            float t = v2; v2 = v3; v3 = t;
        }
    }

    int t = k >> 5, j = k & 7, lk = (k >> 3) & 3;
#pragma unroll
    for (int r = 0; r < 4; ++r) {
        int n = a0 + r;
        int u = n >> 4;
        int ls = lk * 16 + (n & 15);
        float val = (r == 0) ? v0 : (r == 1) ? v1 : (r == 2) ? v2 : v3;
        Bp[(((u * 8 + t) * 64) + ls) * 8 + j] = f2bf(val);
    }
}

// convert one thread's 8 floats of a 16-row tile, store swizzled, and
// publish fp32 row norm (R12-verified numerics path).
__device__ __forceinline__ void cvt_store(const float4& a, const float4& b,
                                          unsigned short (*Xp)[256],
                                          float* NrmT, int sr, int qt) {
    float ss = fmaf(a.x, a.x, fmaf(a.y, a.y, fmaf(a.z, a.z, a.w * a.w)));
    ss = fmaf(b.x, b.x, fmaf(b.y, b.y, fmaf(b.z, b.z, fmaf(b.w, b.w, ss))));
    bf16x8 h;
    h[0] = (short)f2bf(a.x); h[1] = (short)f2bf(a.y);
    h[2] = (short)f2bf(a.z); h[3] = (short)f2bf(a.w);
    h[4] = (short)f2bf(b.x); h[5] = (short)f2bf(b.y);
    h[6] = (short)f2bf(b.z); h[7] = (short)f2bf(b.w);
    *(bf16x8*)&Xp[sr][(qt ^ (sr & 7)) * 8] = h;       // bijective XOR swizzle
    ss += __shfl_xor(ss, 1);
    ss += __shfl_xor(ss, 2);
    ss += __shfl_xor(ss, 4);
    ss += __shfl_xor(ss, 8);
    ss += __shfl_xor(ss, 16);
    if (qt == 0) NrmT[sr] = ss;
}

// ---------------------------------------------------------------------------
// Main (R18): involution (z = 1 - 2*P-/||x||^2, only u-blocks 8..15) on the
// R13 pipeline -> uf is ONE u-block/wave (32 VGPR), fitting the 85-reg cap
// of __launch_bounds__(512,6) = 3 blocks/CU. 1024 blocks x 512 thr x 64
// samples (4 tiles of 16), depth-2 prefetch, lgkm-only barriers.
// ---------------------------------------------------------------------------
__global__ __launch_bounds__(512, 6) void qnn_main(
    const float* __restrict__ x, const unsigned short* __restrict__ Bp,
    const float* __restrict__ W1, const float* __restrict__ b1,
    const float* __restrict__ W2, const float* __restrict__ b2,
    float* __restrict__ out) {
    __shared__ __align__(16) unsigned short Xs[2][16][256];   // 16 KB
    __shared__ float Qpart[8][64];                            // 2 KB
    __shared__ float Nrm[64];                                 // 256 B

    int tid = threadIdx.x;
    int l = tid & 63, w = tid >> 6;        // wave 0..7
    int sr = tid >> 5, qt = tid & 31;      // staging: row 0..15, 8-float chunk
    size_t base = (size_t)blockIdx.x * 64 * 256;   // 64 samples/block
    const float* xst = x + base + (size_t)sr * 256 + qt * 8;

    // ---- U fragment: u-block 8+w (minus half), loaded once (32 VGPR) ----
    const unsigned short* up = Bp + (size_t)(8 + w) * 4096 + l * 8;
    bf16x8 uf[8];
#pragma unroll
    for (int t = 0; t < 8; ++t) uf[t] = *(const bf16x8*)(up + t * 512);

    // ---- prologue: tiles 0,1 prefetched; tile 0 converted to LDS ----
    float4 pf[2][2];
    pf[0][0] = *(const float4*)(xst);
    pf[0][1] = *(const float4*)(xst + 4);
    pf[1][0] = *(const float4*)(xst + 4096);
    pf[1][1] = *(const float4*)(xst + 4100);
    cvt_store(pf[0][0], pf[0][1], Xs[0], Nrm, sr, qt);
    wg_barrier();

    int row = l & 15, kg = l >> 4;

    // ---- 4-tile pipeline: prefetch(t+2) -> compute(t) -> cvt_store(t+1) ----
#pragma unroll
    for (int t = 0; t < 4; ++t) {
        if (t + 2 < 4) {
            pf[t & 1][0] = *(const float4*)(xst + (size_t)(t + 2) * 4096);
            pf[t & 1][1] = *(const float4*)(xst + (size_t)(t + 2) * 4096 + 4);
        }
        {   // compute tile t: 8 ksteps x 1 builtin MFMA (one u-block)
            const unsigned short* rp = &Xs[t & 1][row][0];
            f32x4 a0 = {0.f, 0.f, 0.f, 0.f};
#pragma unroll
            for (int ks = 0; ks < 8; ++ks) {
                bf16x8 xf = *(const bf16x8*)(rp + (((ks << 2) | kg) ^ (row & 7)) * 8);
                a0 = __builtin_amdgcn_mfma_f32_16x16x32_bf16(uf[ks], xf, a0, 0, 0, 0);
            }
            float q = 0.f;
#pragma unroll
            for (int j = 0; j < 4; ++j) q = fmaf(a0[j], a0[j], q);
            q += __shfl_xor(q, 16);        // reduce the 4 n-row groups
            q += __shfl_xor(q, 32);
            if (l < 16) Qpart[w][t * 16 + l] = q;
        }
        if (t + 1 < 4)
            cvt_store(pf[(t + 1) & 1][0], pf[(t + 1) & 1][1],
                      Xs[(t + 1) & 1], Nrm + (t + 1) * 16, sr, qt);
        wg_barrier();
    }

    // ---- epilogue: z = 1 - 2*P-/||x||^2, MLP, sigmoid ----
    if (tid < 64) {
        float pm = Qpart[0][tid] + Qpart[1][tid] + Qpart[2][tid] + Qpart[3][tid]
                 + Qpart[4][tid] + Qpart[5][tid] + Qpart[6][tid] + Qpart[7][tid];
        float z = 1.f - 2.f * pm / Nrm[tid];
        float o = b2[0];
#pragma unroll
        for (int jj = 0; jj < 16; ++jj) {
            float h = fmaf(z, W1[jj], b1[jj]);
            h = h > 0.f ? h : 0.f;
            o = fmaf(W2[jj], h, o);
        }
        out[(size_t)blockIdx.x * 64 + tid] = 1.f / (1.f + expf(-o));
    }
}

extern "C" void kernel_launch(void* const* d_in, const int* in_sizes, int n_in,
                              void* d_out, int out_size, void* d_ws, size_t ws_size,
                              hipStream_t stream) {
    const float* x   = (const float*)d_in[0];
    const float* wts = (const float*)d_in[1];
    const float* W1  = (const float*)d_in[2];
    const float* b1  = (const float*)d_in[3];
    const float* W2  = (const float*)d_in[4];
    const float* b2  = (const float*)d_in[5];
    float* out = (float*)d_out;
    unsigned short* Bp = (unsigned short*)d_ws;   // 65536 bf16 = 128 KB

    int B = in_sizes[0] >> 8;        // 65536 samples
    qnn_setup<<<64, 256, 0, stream>>>(wts, Bp);
    qnn_main<<<B / 64, 512, 0, stream>>>(x, Bp, W1, b1, W2, b2, out);
}